// Round 9
// baseline (256.558 us; speedup 1.0000x reference)
//
#include <hip/hip_runtime.h>
#include <math.h>

#define EPSF 1e-9f
#define KK 128
#define MTOP 10   // m

// R16 = R12 with the spill removed (launch_bounds (256,8)->(256,4)).
// Evidence across R7-R15: VALUBusy*dur invariant at 36-39us in EVERY
// structure; memory/occupancy/pipelining levers all dead. The kernel is
// VALU-instruction-count bound: bisection (~1900 instrs) > GEMM (1280 FMA),
// plus S-broadcast LDS reads + addr math + combine shuffles. R12 attacked
// exactly this and passed (absmax 0.0) but launch_bounds(256,8) capped
// VGPR at 64 -> alloc 32 -> 6.2MB/dispatch scratch spills (WRITE_SIZE).
// Fix: (256,4) = 128-VGPR cap; peak need ~60-70.
//
// Decomposition (R12, verified): wave = 5 rows x all-128-k; lane owns 2 cols.
//  * S GEMM operands wave-uniform -> readfirstlane base -> s_load (SMEM,
//    constant cache). Zero LDS S-reads, zero S-address VALU.
//  * P via DMA double-buffer (16-row chunks), ds_read_b64 folded offsets.
//  * No k-combine shuffles, no identity divergence; identity |S| from
//    global float2 (coalesced, L3-hot).
//  * accL (k 0..63) + accH (k 64..127), added at end (rounding parity).
//  * Lockstep ballot bisection + EXACT early-exit: count(>mid)==10 ->
//    m11 = masked butterfly-max of values <= mid (wave-uniform branch).
// MANDATORY counter checks this round: VGPR 60-90 (not 32!), WRITE_SIZE
// ~64KB (not MB). LESSONS: never starve the VGPR cap (R9/R12); coverage
// check: 8 chunks x 16 rows = 128 (R13); workspace stays 2*B floats.

#define GLDS16(G, L) __builtin_amdgcn_global_load_lds(                    \
    (const __attribute__((address_space(1))) void*)(G),                   \
    (__attribute__((address_space(3))) void*)(L), 16, 0, 0)

// Wave w stages rows 4w..4w+3 of 16-row chunk T: 2 issues x 2 rows.
// Per-lane global source; wave-uniform LDS dest (HW adds lane*16).
#define STAGE(T, BUF)                                                     \
    { GLDS16(Pb + (size_t)((T) * 16 + 4 * wave + 0 + l5) * KK + (lx << 2),\
             &sP[BUF][(4 * wave + 0) * KK]);                              \
      GLDS16(Pb + (size_t)((T) * 16 + 4 * wave + 2 + l5) * KK + (lx << 2),\
             &sP[BUF][(4 * wave + 2) * KK]); }

// 8 k-values of chunk T, half H (0/1): p from LDS (b64, folded offsets),
// s from scalar loads (wave-uniform). Per-output k-ascending FMA order.
#define SUBCHUNK(BUFP, T, H, A0, A1)                                      \
    {                                                                     \
        const float* __restrict__ pb = (BUFP) + (H) * 8 * KK + j2;        \
        float2 p0 = *(const float2*)(pb + 0 * KK);                        \
        float2 p1 = *(const float2*)(pb + 1 * KK);                        \
        float2 p2 = *(const float2*)(pb + 2 * KK);                        \
        float2 p3 = *(const float2*)(pb + 3 * KK);                        \
        float2 p4 = *(const float2*)(pb + 4 * KK);                        \
        float2 p5 = *(const float2*)(pb + 5 * KK);                        \
        float2 p6 = *(const float2*)(pb + 6 * KK);                        \
        float2 p7 = *(const float2*)(pb + 7 * KK);                        \
        _Pragma("unroll")                                                 \
        for (int r = 0; r < 5; ++r) {                                     \
            const float* __restrict__ su = Su + r * KK + (T) * 16 + (H) * 8; \
            float4 sA = *(const float4*)(su);                             \
            float4 sB = *(const float4*)(su + 4);                         \
            A0[r] = fmaf(sA.x, p0.x, A0[r]); A1[r] = fmaf(sA.x, p0.y, A1[r]); \
            A0[r] = fmaf(sA.y, p1.x, A0[r]); A1[r] = fmaf(sA.y, p1.y, A1[r]); \
            A0[r] = fmaf(sA.z, p2.x, A0[r]); A1[r] = fmaf(sA.z, p2.y, A1[r]); \
            A0[r] = fmaf(sA.w, p3.x, A0[r]); A1[r] = fmaf(sA.w, p3.y, A1[r]); \
            A0[r] = fmaf(sB.x, p4.x, A0[r]); A1[r] = fmaf(sB.x, p4.y, A1[r]); \
            A0[r] = fmaf(sB.y, p5.x, A0[r]); A1[r] = fmaf(sB.y, p5.y, A1[r]); \
            A0[r] = fmaf(sB.z, p6.x, A0[r]); A1[r] = fmaf(sB.z, p6.y, A1[r]); \
            A0[r] = fmaf(sB.w, p7.x, A0[r]); A1[r] = fmaf(sB.w, p7.y, A1[r]); \
        }                                                                 \
    }

__global__ __launch_bounds__(256, 4) void fused_kernel(
    const float* __restrict__ y_pred, const float* __restrict__ y_true,
    const float* __restrict__ P, const float* __restrict__ samples,
    float* __restrict__ partial /* [2*B]: per-block {logmse_i, penalty_i} */)
{
    const int tid  = threadIdx.x;
    const int wave = tid >> 6;
    const int lane = tid & 63;
    const int b    = blockIdx.x;
    const int r0   = wave * 5;
    const int j2   = lane << 1;      // this lane's column pair (floats)
    const int l5   = lane >> 5;      // staging: row-within-issue
    const int lx   = lane & 31;      // staging: 16B slot within row

    const float* __restrict__ Pb = P + ((size_t)b << 14);            // b*128*128
    const float* __restrict__ Sb = samples + (size_t)b * (20 * KK);  // b*20*128
    // Wave-uniform S base: readfirstlane makes uniformity provable so the
    // compiler selects scalar (SMEM) loads for the GEMM operands.
    const int ru = __builtin_amdgcn_readfirstlane(r0);
    const float* __restrict__ Su = Sb + (size_t)ru * KK;

    __shared__ float sP[2][16 * KK]; // double-buffered 16-row P chunk (8KB ea)
    __shared__ float red[4];

    float accL0[5], accL1[5], accH0[5], accH1[5];
#pragma unroll
    for (int r = 0; r < 5; ++r) {
        accL0[r] = 0.f; accL1[r] = 0.f; accH0[r] = 0.f; accH1[r] = 0.f;
    }

    // ---- prologue: DMA chunk 0 ----
    STAGE(0, 0);
    __syncthreads();

    int cur = 0;
    // ---- chunks 0..3 (k 0..63) -> accL ----
#pragma unroll 1
    for (int t = 0; t < 4; ++t) {
        STAGE(t + 1, cur ^ 1);
        const float* __restrict__ bufp = &sP[0][0] + cur * (16 * KK);
        SUBCHUNK(bufp, t, 0, accL0, accL1)
        SUBCHUNK(bufp, t, 1, accL0, accL1)
        __syncthreads();
        cur ^= 1;
    }
    // ---- chunks 4..6 (k 64..111) -> accH, still prefetching ----
#pragma unroll 1
    for (int t = 4; t < 7; ++t) {
        STAGE(t + 1, cur ^ 1);
        const float* __restrict__ bufp = &sP[0][0] + cur * (16 * KK);
        SUBCHUNK(bufp, t, 0, accH0, accH1)
        SUBCHUNK(bufp, t, 1, accH0, accH1)
        __syncthreads();
        cur ^= 1;
    }
    // ---- epilogue chunk 7 ----
    {
        const float* __restrict__ bufp = &sP[0][0] + cur * (16 * KK);
        SUBCHUNK(bufp, 7, 0, accH0, accH1)
        SUBCHUNK(bufp, 7, 1, accH0, accH1)
    }

    // ---- magnitudes: 2 computed cols + 2 identity cols per lane ----
    float w0[5], w1[5], w2[5], w3[5];
#pragma unroll
    for (int r = 0; r < 5; ++r) {
        float2 sid = *(const float2*)(Sb + (size_t)(r0 + r) * KK + j2);
        w0[r] = fabsf(accL0[r] + accH0[r]);
        w1[r] = fabsf(accL1[r] + accH1[r]);
        w2[r] = fabsf(sid.x);
        w3[r] = fabsf(sid.y);
    }

    // ---- m1 per row: lane max + 6-shfl butterfly ----
    float mx[5];
#pragma unroll
    for (int r = 0; r < 5; ++r) {
        float lm = fmaxf(fmaxf(w0[r], w1[r]), fmaxf(w2[r], w3[r]));
#pragma unroll
        for (int d = 32; d >= 1; d >>= 1)
            lm = fmaxf(lm, __shfl_xor(lm, d, 64));
        mx[r] = lm;
    }

    // ---- m11 per row: lockstep ballot bisection + exact early-exit ----
    // count(>mid)==10  ->  m11 = max(values <= mid)  (masked butterfly).
    // Ties never produce count==10 -> fall through to full convergence.
    unsigned lo[5], hi[5];
    float m11v[5];
    int act[5];
#pragma unroll
    for (int r = 0; r < 5; ++r) {
        lo[r] = 0u; hi[r] = __float_as_uint(mx[r]); m11v[r] = 0.f; act[r] = 1;
    }

    while ((act[0] && lo[0] < hi[0]) || (act[1] && lo[1] < hi[1]) ||
           (act[2] && lo[2] < hi[2]) || (act[3] && lo[3] < hi[3]) ||
           (act[4] && lo[4] < hi[4])) {
#pragma unroll
        for (int r = 0; r < 5; ++r) {
            if (act[r] && lo[r] < hi[r]) {
                unsigned mid = lo[r] + ((hi[r] - lo[r] + 1u) >> 1);
                float mf = __uint_as_float(mid);
                int cnt = __popcll(__ballot(w0[r] > mf)) + __popcll(__ballot(w1[r] > mf))
                        + __popcll(__ballot(w2[r] > mf)) + __popcll(__ballot(w3[r] > mf));
                if (cnt == MTOP) {
                    float t0 = (w0[r] <= mf) ? w0[r] : 0.f;
                    float t1 = (w1[r] <= mf) ? w1[r] : 0.f;
                    float t2 = (w2[r] <= mf) ? w2[r] : 0.f;
                    float t3 = (w3[r] <= mf) ? w3[r] : 0.f;
                    float lm = fmaxf(fmaxf(t0, t1), fmaxf(t2, t3));
#pragma unroll
                    for (int d = 32; d >= 1; d >>= 1)
                        lm = fmaxf(lm, __shfl_xor(lm, d, 64));
                    m11v[r] = lm;
                    act[r] = 0;
                } else {
                    bool g = cnt >= (MTOP + 1);
                    lo[r] = g ? mid : lo[r];
                    hi[r] = g ? hi[r] : mid - 1u;
                }
            }
        }
    }

    float hmax = 0.f;
#pragma unroll
    for (int r = 0; r < 5; ++r) {
        float m11 = act[r] ? __uint_as_float(lo[r] + 1u) : m11v[r];
        hmax = fmaxf(hmax, mx[r] / (m11 + EPSF));  // wave-uniform
    }

    // ---- combine 4 waves; per-block partials (no atomics) ----
    if (lane == 0) red[wave] = hmax;
    __syncthreads();
    if (tid == 0) {
        float hb  = fmaxf(fmaxf(red[0], red[1]), fmaxf(red[2], red[3]));
        float ypv = y_pred[b];
        float yp  = fmaxf(ypv, EPSF);
        float yt  = fmaxf(y_true[b], EPSF);
        float d   = log2f(yt) - log2f(yp);
        partial[2 * b]     = d * d;
        partial[2 * b + 1] = fmaxf(hb - ypv, 0.f);
    }
}

__global__ __launch_bounds__(256) void finalize_kernel(
    const float* __restrict__ partial, float* __restrict__ out, float invB)
{
    const int t = threadIdx.x;
    float sl = 0.f, sp = 0.f;
#pragma unroll
    for (int i = 0; i < 8; ++i) {
        float2 v = *(const float2*)(partial + 2 * (t + i * 256));
        sl += v.x; sp += v.y;
    }
#pragma unroll
    for (int d = 32; d >= 1; d >>= 1) {
        sl += __shfl_xor(sl, d, 64);
        sp += __shfl_xor(sp, d, 64);
    }
    __shared__ float rl[4], rp[4];
    const int w = t >> 6;
    if ((t & 63) == 0) { rl[w] = sl; rp[w] = sp; }
    __syncthreads();
    if (t == 0) {
        float L = (rl[0] + rl[1] + rl[2] + rl[3]) * invB;
        float V = (rp[0] + rp[1] + rp[2] + rp[3]) * invB;
        out[0] = L + 0.5f * V;
        out[1] = L;
        out[2] = V;
    }
}

extern "C" void kernel_launch(void* const* d_in, const int* in_sizes, int n_in,
                              void* d_out, int out_size, void* d_ws, size_t ws_size,
                              hipStream_t stream) {
    const float* y_pred  = (const float*)d_in[0];
    const float* y_true  = (const float*)d_in[1];
    const float* P       = (const float*)d_in[2];
    const float* samples = (const float*)d_in[3];
    const int B = in_sizes[0];           // y_pred has B elements

    float* partial = (float*)d_ws;       // 2*B floats, fully overwritten

    fused_kernel<<<B, 256, 0, stream>>>(y_pred, y_true, P, samples, partial);
    finalize_kernel<<<1, 256, 0, stream>>>(partial, (float*)d_out, 1.0f / (float)B);
}

// Round 10
// 233.496 us; speedup vs baseline: 1.0988x; 1.0988x over previous
//
#include <hip/hip_runtime.h>
#include <math.h>

#define EPSF 1e-9f
#define KK 128
#define MTOP 10   // m

// R17 = R11 (82us verified control) + ONE isolated change: exact early-exit
// in the lockstep bisection.
//
// Model (R7-R16): duration tracks TOTAL per-wave issue count. All memory
// restructures (R10/R11/R14/R15) land 82-94us; occupancy 20-72% irrelevant;
// VALUBusy pinned 40-47% with DS/SALU/VMEM/branch issue filling the rest of
// the port. Biggest instruction blocks: GEMM ~2.6k cycles, bisection ~2-3k
// (31 iters x 5 rows x ~14 instrs). This round halves the bisection:
//   count(>mid)==10  ->  m11 = max{v <= mid}  (exact; one masked butterfly),
// then PARK the row: lo=hi=pattern(m11)-1, so the unchanged while-condition
// retires it and the final m11 = uint_as_float(lo+1) returns it exactly.
// Expected iters: ~2^30 range -> (v10,v11) pattern gap ~2^17 => ~13-16 iters
// (vs 31). Ties (v10==v11) never give count==10 -> verified full path -> exact.
// Parked-state stability: mid=lo, mf=m11-ulp, count>=11 -> g -> lo=lo. Stable.
// R16 lesson recorded: scalar-S SMEM in the GEMM loop shares lgkmcnt with
// ds_read (out-of-order SMEM => lgkmcnt(0) drains) - don't mix.
//
// LESSONS: hipcc de-pipelines register prefetch (R9/R10) -> DMA only;
// launch_bounds caps VGPR - never starve (R12); staging must cover all 128
// rows (R13); workspace stays 2*B floats; compile-time reg-array indices.

#define GLDS16(G, L) __builtin_amdgcn_global_load_lds(                    \
    (const __attribute__((address_space(1))) void*)(G),                   \
    (__attribute__((address_space(3))) void*)(L), 16, 0, 0)

// Wave w stages local rows 4w+2I, 4w+2I+1 of chunk T into sP[BUF].
// Global row = 8T + rowoff + local_row (rowoff folds the hi-half offset).
// Per-lane global addr; WAVE-UNIFORM LDS base (HW adds lane*16).
#define STAGE_ISSUE(T, BUF, I)                                            \
    GLDS16(Pb + (size_t)(((T) << 3) + rowoff + (wave << 2) + ((I) << 1)   \
                         + l5) * KK + (lx << 2),                          \
           &sP[BUF][((wave << 2) + ((I) << 1)) * KK])
#define STAGE_CHUNK(T, BUF) { STAGE_ISSUE(T, BUF, 0); STAGE_ISSUE(T, BUF, 1); }

// One 4-k FMA group of chunk T, group G (0/1), p from LDS buffer BUF.
#define FMA5G(T, BUF, G)                                                  \
    {                                                                     \
        const float* pbse = &sP[BUF][((sg << 3) + ((G) << 2)) * KK + j4]; \
        float4 p0 = *(const float4*)(pbse + 0 * KK);                      \
        float4 p1 = *(const float4*)(pbse + 1 * KK);                      \
        float4 p2 = *(const float4*)(pbse + 2 * KK);                      \
        float4 p3 = *(const float4*)(pbse + 3 * KK);                      \
        const int soff = kbase + ((T) << 3) + ((G) << 2);                 \
        _Pragma("unroll")                                                 \
        for (int r = 0; r < 5; ++r) {                                     \
            float4 s = *(const float4*)&sS[(r0 + r) * KK + soff];         \
            acc[r].x = fmaf(s.x, p0.x, acc[r].x);                         \
            acc[r].y = fmaf(s.x, p0.y, acc[r].y);                         \
            acc[r].z = fmaf(s.x, p0.z, acc[r].z);                         \
            acc[r].w = fmaf(s.x, p0.w, acc[r].w);                         \
            acc[r].x = fmaf(s.y, p1.x, acc[r].x);                         \
            acc[r].y = fmaf(s.y, p1.y, acc[r].y);                         \
            acc[r].z = fmaf(s.y, p1.z, acc[r].z);                         \
            acc[r].w = fmaf(s.y, p1.w, acc[r].w);                         \
            acc[r].x = fmaf(s.z, p2.x, acc[r].x);                         \
            acc[r].y = fmaf(s.z, p2.y, acc[r].y);                         \
            acc[r].z = fmaf(s.z, p2.z, acc[r].z);                         \
            acc[r].w = fmaf(s.z, p2.w, acc[r].w);                         \
            acc[r].x = fmaf(s.w, p3.x, acc[r].x);                         \
            acc[r].y = fmaf(s.w, p3.y, acc[r].y);                         \
            acc[r].z = fmaf(s.w, p3.z, acc[r].z);                         \
            acc[r].w = fmaf(s.w, p3.w, acc[r].w);                         \
        }                                                                 \
    }

__global__ __launch_bounds__(256, 6) void fused_kernel(
    const float* __restrict__ y_pred, const float* __restrict__ y_true,
    const float* __restrict__ P, const float* __restrict__ samples,
    float* __restrict__ partial /* [2*B]: per-block {logmse_i, penalty_i} */)
{
    const int tid   = threadIdx.x;
    const int wave  = tid >> 6;
    const int lane  = tid & 63;
    const int b     = blockIdx.x;
    const int r0    = wave * 5;
    const int sg    = lane >> 5;     // k-segment of the half-wave
    const int c     = lane & 31;     // column group
    const int j4    = c << 2;
    const int kbase = sg << 6;       // 0 or 64
    const int l5    = lane >> 5;     // staging: row-within-issue
    const int lx    = lane & 31;     // staging: 16B slot within row
    const int rowoff = (wave >= 2) ? 56 : 0;  // hi-half rows: 64+(il-8)=56+il

    const float* __restrict__ Pb = P + ((size_t)b << 14);            // b*128*128
    const float* __restrict__ Sb = samples + (size_t)b * (20 * KK);  // b*20*128

    __shared__ float sS[20 * KK];    // S rows: broadcast + identity values
    __shared__ float sP[2][16 * KK]; // double-buffered P chunk (16 rows)
    __shared__ float red[4];

    // ---- stage S into LDS, block-cooperative, coalesced float2 ----
#pragma unroll
    for (int i = 0; i < 5; ++i) {
        const int idx = (i * 256 + tid) * 2;
        *(float2*)&sS[idx] = *(const float2*)(Sb + idx);
    }

    float4 acc[5];
#pragma unroll
    for (int r = 0; r < 5; ++r) acc[r] = make_float4(0.f, 0.f, 0.f, 0.f);

    // ---- prologue: DMA chunk 0; barrier drains DMA + sS writes ----
    STAGE_CHUNK(0, 0);
    __syncthreads();

    // ---- 2-phase pipelined GEMM: issue(t+1) || compute(t) ----
    int cur = 0;
#pragma unroll 1
    for (int t = 0; t < 7; ++t) {
        STAGE_CHUNK(t + 1, cur ^ 1);   // DMA in flight under the FMAs
        FMA5G(t, cur, 0)
        FMA5G(t, cur, 1)
        __syncthreads();               // vmcnt(0)+barrier: chunk t+1 ready
        cur ^= 1;
    }
    FMA5G(7, cur, 0)                   // epilogue chunk, no prefetch
    FMA5G(7, cur, 1)

    // ---- combine k-halves; upper half-wave switches to identity values ----
    float w0[5], w1[5], w2[5], w3[5];
#pragma unroll
    for (int r = 0; r < 5; ++r) {
        float ax = acc[r].x + __shfl_xor(acc[r].x, 32, 64);
        float ay = acc[r].y + __shfl_xor(acc[r].y, 32, 64);
        float az = acc[r].z + __shfl_xor(acc[r].z, 32, 64);
        float aw = acc[r].w + __shfl_xor(acc[r].w, 32, 64);
        float4 idv = *(const float4*)&sS[(r0 + r) * KK + j4];
        w0[r] = fabsf(sg ? idv.x : ax);
        w1[r] = fabsf(sg ? idv.y : ay);
        w2[r] = fabsf(sg ? idv.z : az);
        w3[r] = fabsf(sg ? idv.w : aw);
    }

    // ---- m1 per row: lane max + 6-shfl butterfly (5 chains interleave) ----
    float mx[5];
#pragma unroll
    for (int r = 0; r < 5; ++r) {
        float lm = fmaxf(fmaxf(w0[r], w1[r]), fmaxf(w2[r], w3[r]));
#pragma unroll
        for (int d = 32; d >= 1; d >>= 1)
            lm = fmaxf(lm, __shfl_xor(lm, d, 64));
        mx[r] = lm;
    }

    // ---- m11 per row: LOCKSTEP ballot bisection + exact early-exit ----
    // cnt==10 -> m11 = max{v<=mid} (masked butterfly, exact), then PARK:
    // lo=hi=pattern(m11)-1 so the loop retires the row and the final
    // lo+1 read returns m11. Ties never hit cnt==10 -> verified path.
    unsigned lo[5], hi[5];
#pragma unroll
    for (int r = 0; r < 5; ++r) { lo[r] = 0u; hi[r] = __float_as_uint(mx[r]); }

    while (lo[0] < hi[0] || lo[1] < hi[1] || lo[2] < hi[2] ||
           lo[3] < hi[3] || lo[4] < hi[4]) {
#pragma unroll
        for (int r = 0; r < 5; ++r) {
            unsigned mid = lo[r] + ((hi[r] - lo[r] + 1u) >> 1);
            float mf = __uint_as_float(mid);
            int cnt = __popcll(__ballot(w0[r] > mf)) + __popcll(__ballot(w1[r] > mf))
                    + __popcll(__ballot(w2[r] > mf)) + __popcll(__ballot(w3[r] > mf));
            if (cnt == MTOP) {
                float t0 = (w0[r] <= mf) ? w0[r] : 0.f;
                float t1 = (w1[r] <= mf) ? w1[r] : 0.f;
                float t2 = (w2[r] <= mf) ? w2[r] : 0.f;
                float t3 = (w3[r] <= mf) ? w3[r] : 0.f;
                float lm = fmaxf(fmaxf(t0, t1), fmaxf(t2, t3));
#pragma unroll
                for (int d = 32; d >= 1; d >>= 1)
                    lm = fmaxf(lm, __shfl_xor(lm, d, 64));
                unsigned pm1 = __float_as_uint(lm) - 1u;   // park the row
                lo[r] = pm1;
                hi[r] = pm1;
            } else {
                bool g = cnt >= (MTOP + 1);
                lo[r] = g ? mid : lo[r];
                hi[r] = g ? hi[r] : mid - 1u;
            }
        }
    }

    float hmax = 0.f;
#pragma unroll
    for (int r = 0; r < 5; ++r) {
        float m11 = __uint_as_float(lo[r] + 1u);   // exact 11th-largest
        hmax = fmaxf(hmax, mx[r] / (m11 + EPSF));  // wave-uniform
    }

    // ---- combine 4 waves; per-block partials (no atomics) ----
    if (lane == 0) red[wave] = hmax;
    __syncthreads();
    if (tid == 0) {
        float hb  = fmaxf(fmaxf(red[0], red[1]), fmaxf(red[2], red[3]));
        float ypv = y_pred[b];
        float yp  = fmaxf(ypv, EPSF);
        float yt  = fmaxf(y_true[b], EPSF);
        float d   = log2f(yt) - log2f(yp);
        partial[2 * b]     = d * d;
        partial[2 * b + 1] = fmaxf(hb - ypv, 0.f);
    }
}

__global__ __launch_bounds__(256) void finalize_kernel(
    const float* __restrict__ partial, float* __restrict__ out, float invB)
{
    const int t = threadIdx.x;
    float sl = 0.f, sp = 0.f;
#pragma unroll
    for (int i = 0; i < 8; ++i) {
        float2 v = *(const float2*)(partial + 2 * (t + i * 256));
        sl += v.x; sp += v.y;
    }
#pragma unroll
    for (int d = 32; d >= 1; d >>= 1) {
        sl += __shfl_xor(sl, d, 64);
        sp += __shfl_xor(sp, d, 64);
    }
    __shared__ float rl[4], rp[4];
    const int w = t >> 6;
    if ((t & 63) == 0) { rl[w] = sl; rp[w] = sp; }
    __syncthreads();
    if (t == 0) {
        float L = (rl[0] + rl[1] + rl[2] + rl[3]) * invB;
        float V = (rp[0] + rp[1] + rp[2] + rp[3]) * invB;
        out[0] = L + 0.5f * V;
        out[1] = L;
        out[2] = V;
    }
}

extern "C" void kernel_launch(void* const* d_in, const int* in_sizes, int n_in,
                              void* d_out, int out_size, void* d_ws, size_t ws_size,
                              hipStream_t stream) {
    const float* y_pred  = (const float*)d_in[0];
    const float* y_true  = (const float*)d_in[1];
    const float* P       = (const float*)d_in[2];
    const float* samples = (const float*)d_in[3];
    const int B = in_sizes[0];           // y_pred has B elements

    float* partial = (float*)d_ws;       // 2*B floats, fully overwritten

    fused_kernel<<<B, 256, 0, stream>>>(y_pred, y_true, P, samples, partial);
    finalize_kernel<<<1, 256, 0, stream>>>(partial, (float*)d_out, 1.0f / (float)B);
}

// Round 11
// 233.175 us; speedup vs baseline: 1.1003x; 1.0014x over previous
//
#include <hip/hip_runtime.h>
#include <math.h>

#define EPSF 1e-9f
#define KK 128
#define MTOP 10   // m

// R18 = R17 (82us, absmax 0) with 8-row chunks -> LDS 18.4KB -> 8 blocks/CU.
//
// R17 post-mortem: early-exit bisection cut VALUBusy 44.7->31.4% (=10us of
// issue removed) at IDENTICAL 82us -> issue-count theory dead. Surviving
// model: correlated-stall-bound. Each block's 4 waves lockstep through an
// 8-step DMA-drain chain (~0.9us exposed per chunk => ~10us critical path);
// only ~3.5 blocks resident (27KB LDS) -> stalls don't interleave. Predicted
// duty 3.2/10 = 32% == measured VALUBusy 31%. Fix: 8 resident blocks/CU so
// independent blocks' stalls interleave. Unlike R9/R12 occupancy attempts
// (confounded: de-pipelined loads / spills), VALU is now LOW -> headroom.
//  * Chunk = 8 rows: 4 lo-half (4t..4t+3) + 4 hi-half (64+4t..64+4t+3).
//    Wave w stages local rows {2w,2w+1} via ONE GLDS16 (1KB). 16 chunks.
//    Coverage: 16 x 8 = 128 rows, waves 0-1 lo, 2-3 hi (rowoff=60). (R13!)
//  * Per-half k-group sequence stays 0,4,...,60 ascending => accumulation
//    BIT-IDENTICAL to R17/R11. Bisection/combine/epilogue verbatim R17.
//  * launch_bounds(256,8): VGPR cap 64; R17 measured 40. MANDATORY check:
//    WRITE_SIZE ~64KB (no spill), VGPR <= 64. If spilled -> revert (256,6).
// LESSONS: hipcc de-pipelines reg prefetch -> DMA only; never starve VGPR
// cap; no SMEM in DS inner loop (R16); coverage check; 2*B workspace.

#define GLDS16(G, L) __builtin_amdgcn_global_load_lds(                    \
    (const __attribute__((address_space(1))) void*)(G),                   \
    (__attribute__((address_space(3))) void*)(L), 16, 0, 0)

// Wave w stages local rows {2w, 2w+1} of 8-row chunk T into sP[BUF].
// Global row = 4T + 2w + l5 + (wave>=2 ? 60 : 0). Per-lane global addr;
// WAVE-UNIFORM LDS base (HW adds lane*16: lanes 0-31 row 2w, 32-63 row 2w+1).
#define STAGE_CHUNK(T, BUF)                                               \
    GLDS16(Pb + (size_t)(((T) << 2) + (wave << 1) + l5 + rowoff) * KK     \
               + (lx << 2),                                               \
           &sP[BUF][(wave << 1) * KK])

// Chunk T: this half-wave's 4 k-values (k = kbase + 4T .. +3).
// Local P rows sg*4..sg*4+3; s from sS at soff. k-ascending FMA order.
#define FMA5G(T, BUF)                                                     \
    {                                                                     \
        const float* pbse = &sP[BUF][(sg << 2) * KK + j4];                \
        float4 p0 = *(const float4*)(pbse + 0 * KK);                      \
        float4 p1 = *(const float4*)(pbse + 1 * KK);                      \
        float4 p2 = *(const float4*)(pbse + 2 * KK);                      \
        float4 p3 = *(const float4*)(pbse + 3 * KK);                      \
        const int soff = kbase + ((T) << 2);                              \
        _Pragma("unroll")                                                 \
        for (int r = 0; r < 5; ++r) {                                     \
            float4 s = *(const float4*)&sS[(r0 + r) * KK + soff];         \
            acc[r].x = fmaf(s.x, p0.x, acc[r].x);                         \
            acc[r].y = fmaf(s.x, p0.y, acc[r].y);                         \
            acc[r].z = fmaf(s.x, p0.z, acc[r].z);                         \
            acc[r].w = fmaf(s.x, p0.w, acc[r].w);                         \
            acc[r].x = fmaf(s.y, p1.x, acc[r].x);                         \
            acc[r].y = fmaf(s.y, p1.y, acc[r].y);                         \
            acc[r].z = fmaf(s.y, p1.z, acc[r].z);                         \
            acc[r].w = fmaf(s.y, p1.w, acc[r].w);                         \
            acc[r].x = fmaf(s.z, p2.x, acc[r].x);                         \
            acc[r].y = fmaf(s.z, p2.y, acc[r].y);                         \
            acc[r].z = fmaf(s.z, p2.z, acc[r].z);                         \
            acc[r].w = fmaf(s.z, p2.w, acc[r].w);                         \
            acc[r].x = fmaf(s.w, p3.x, acc[r].x);                         \
            acc[r].y = fmaf(s.w, p3.y, acc[r].y);                         \
            acc[r].z = fmaf(s.w, p3.z, acc[r].z);                         \
            acc[r].w = fmaf(s.w, p3.w, acc[r].w);                         \
        }                                                                 \
    }

__global__ __launch_bounds__(256, 8) void fused_kernel(
    const float* __restrict__ y_pred, const float* __restrict__ y_true,
    const float* __restrict__ P, const float* __restrict__ samples,
    float* __restrict__ partial /* [2*B]: per-block {logmse_i, penalty_i} */)
{
    const int tid   = threadIdx.x;
    const int wave  = tid >> 6;
    const int lane  = tid & 63;
    const int b     = blockIdx.x;
    const int r0    = wave * 5;
    const int sg    = lane >> 5;     // k-segment of the half-wave
    const int c     = lane & 31;     // column group
    const int j4    = c << 2;
    const int kbase = sg << 6;       // 0 or 64
    const int l5    = lane >> 5;     // staging: row-within-issue
    const int lx    = lane & 31;     // staging: 16B slot within row
    const int rowoff = (wave >= 2) ? 60 : 0;  // hi-half: 64+4t+2(w-2)+l5

    const float* __restrict__ Pb = P + ((size_t)b << 14);            // b*128*128
    const float* __restrict__ Sb = samples + (size_t)b * (20 * KK);  // b*20*128

    __shared__ float sS[20 * KK];    // S rows: broadcast + identity (10KB)
    __shared__ float sP[2][8 * KK];  // double-buffered 8-row P chunk (4KB ea)
    __shared__ float red[4];

    // ---- stage S into LDS, block-cooperative, coalesced float2 ----
#pragma unroll
    for (int i = 0; i < 5; ++i) {
        const int idx = (i * 256 + tid) * 2;
        *(float2*)&sS[idx] = *(const float2*)(Sb + idx);
    }

    float4 acc[5];
#pragma unroll
    for (int r = 0; r < 5; ++r) acc[r] = make_float4(0.f, 0.f, 0.f, 0.f);

    // ---- prologue: DMA chunk 0; barrier drains DMA + sS writes ----
    STAGE_CHUNK(0, 0);
    __syncthreads();

    // ---- 2-phase pipelined GEMM: issue(t+1) || compute(t), 16 chunks ----
    int cur = 0;
#pragma unroll 1
    for (int t = 0; t < 15; ++t) {
        STAGE_CHUNK(t + 1, cur ^ 1);   // DMA in flight under the FMAs
        FMA5G(t, cur)
        __syncthreads();               // vmcnt(0)+barrier: chunk t+1 ready
        cur ^= 1;
    }
    FMA5G(15, cur)                     // epilogue chunk, no prefetch

    // ---- combine k-halves; upper half-wave switches to identity values ----
    float w0[5], w1[5], w2[5], w3[5];
#pragma unroll
    for (int r = 0; r < 5; ++r) {
        float ax = acc[r].x + __shfl_xor(acc[r].x, 32, 64);
        float ay = acc[r].y + __shfl_xor(acc[r].y, 32, 64);
        float az = acc[r].z + __shfl_xor(acc[r].z, 32, 64);
        float aw = acc[r].w + __shfl_xor(acc[r].w, 32, 64);
        float4 idv = *(const float4*)&sS[(r0 + r) * KK + j4];
        w0[r] = fabsf(sg ? idv.x : ax);
        w1[r] = fabsf(sg ? idv.y : ay);
        w2[r] = fabsf(sg ? idv.z : az);
        w3[r] = fabsf(sg ? idv.w : aw);
    }

    // ---- m1 per row: lane max + 6-shfl butterfly (5 chains interleave) ----
    float mx[5];
#pragma unroll
    for (int r = 0; r < 5; ++r) {
        float lm = fmaxf(fmaxf(w0[r], w1[r]), fmaxf(w2[r], w3[r]));
#pragma unroll
        for (int d = 32; d >= 1; d >>= 1)
            lm = fmaxf(lm, __shfl_xor(lm, d, 64));
        mx[r] = lm;
    }

    // ---- m11 per row: LOCKSTEP ballot bisection + exact early-exit ----
    // cnt==10 -> m11 = max{v<=mid} (masked butterfly, exact), then PARK:
    // lo=hi=pattern(m11)-1 so the loop retires the row and the final
    // lo+1 read returns m11. Ties never hit cnt==10 -> verified path.
    unsigned lo[5], hi[5];
#pragma unroll
    for (int r = 0; r < 5; ++r) { lo[r] = 0u; hi[r] = __float_as_uint(mx[r]); }

    while (lo[0] < hi[0] || lo[1] < hi[1] || lo[2] < hi[2] ||
           lo[3] < hi[3] || lo[4] < hi[4]) {
#pragma unroll
        for (int r = 0; r < 5; ++r) {
            unsigned mid = lo[r] + ((hi[r] - lo[r] + 1u) >> 1);
            float mf = __uint_as_float(mid);
            int cnt = __popcll(__ballot(w0[r] > mf)) + __popcll(__ballot(w1[r] > mf))
                    + __popcll(__ballot(w2[r] > mf)) + __popcll(__ballot(w3[r] > mf));
            if (cnt == MTOP) {
                float t0 = (w0[r] <= mf) ? w0[r] : 0.f;
                float t1 = (w1[r] <= mf) ? w1[r] : 0.f;
                float t2 = (w2[r] <= mf) ? w2[r] : 0.f;
                float t3 = (w3[r] <= mf) ? w3[r] : 0.f;
                float lm = fmaxf(fmaxf(t0, t1), fmaxf(t2, t3));
#pragma unroll
                for (int d = 32; d >= 1; d >>= 1)
                    lm = fmaxf(lm, __shfl_xor(lm, d, 64));
                unsigned pm1 = __float_as_uint(lm) - 1u;   // park the row
                lo[r] = pm1;
                hi[r] = pm1;
            } else {
                bool g = cnt >= (MTOP + 1);
                lo[r] = g ? mid : lo[r];
                hi[r] = g ? hi[r] : mid - 1u;
            }
        }
    }

    float hmax = 0.f;
#pragma unroll
    for (int r = 0; r < 5; ++r) {
        float m11 = __uint_as_float(lo[r] + 1u);   // exact 11th-largest
        hmax = fmaxf(hmax, mx[r] / (m11 + EPSF));  // wave-uniform
    }

    // ---- combine 4 waves; per-block partials (no atomics) ----
    if (lane == 0) red[wave] = hmax;
    __syncthreads();
    if (tid == 0) {
        float hb  = fmaxf(fmaxf(red[0], red[1]), fmaxf(red[2], red[3]));
        float ypv = y_pred[b];
        float yp  = fmaxf(ypv, EPSF);
        float yt  = fmaxf(y_true[b], EPSF);
        float d   = log2f(yt) - log2f(yp);
        partial[2 * b]     = d * d;
        partial[2 * b + 1] = fmaxf(hb - ypv, 0.f);
    }
}

__global__ __launch_bounds__(256) void finalize_kernel(
    const float* __restrict__ partial, float* __restrict__ out, float invB)
{
    const int t = threadIdx.x;
    float sl = 0.f, sp = 0.f;
#pragma unroll
    for (int i = 0; i < 8; ++i) {
        float2 v = *(const float2*)(partial + 2 * (t + i * 256));
        sl += v.x; sp += v.y;
    }
#pragma unroll
    for (int d = 32; d >= 1; d >>= 1) {
        sl += __shfl_xor(sl, d, 64);
        sp += __shfl_xor(sp, d, 64);
    }
    __shared__ float rl[4], rp[4];
    const int w = t >> 6;
    if ((t & 63) == 0) { rl[w] = sl; rp[w] = sp; }
    __syncthreads();
    if (t == 0) {
        float L = (rl[0] + rl[1] + rl[2] + rl[3]) * invB;
        float V = (rp[0] + rp[1] + rp[2] + rp[3]) * invB;
        out[0] = L + 0.5f * V;
        out[1] = L;
        out[2] = V;
    }
}

extern "C" void kernel_launch(void* const* d_in, const int* in_sizes, int n_in,
                              void* d_out, int out_size, void* d_ws, size_t ws_size,
                              hipStream_t stream) {
    const float* y_pred  = (const float*)d_in[0];
    const float* y_true  = (const float*)d_in[1];
    const float* P       = (const float*)d_in[2];
    const float* samples = (const float*)d_in[3];
    const int B = in_sizes[0];           // y_pred has B elements

    float* partial = (float*)d_ws;       // 2*B floats, fully overwritten

    fused_kernel<<<B, 256, 0, stream>>>(y_pred, y_true, P, samples, partial);
    finalize_kernel<<<1, 256, 0, stream>>>(partial, (float*)d_out, 1.0f / (float)B);
}